// Round 1
// baseline (397.474 us; speedup 1.0000x reference)
//
#include <hip/hip_runtime.h>
#include <hip/hip_bf16.h>
#include <math.h>

#define LEN 4096
#define DIM 2048

typedef __attribute__((ext_vector_type(8))) short s16x8;
typedef __attribute__((ext_vector_type(4))) float f32x4;

__device__ inline ushort f2bf(float f) {
  union { float f; unsigned u; } v; v.f = f;
  unsigned r = (v.u + 0x7FFFu + ((v.u >> 16) & 1u)) >> 16;
  return (ushort)r;
}

__device__ inline void gll16(const void* g, void* l) {
  __builtin_amdgcn_global_load_lds(
      (const __attribute__((address_space(1))) void*)g,
      (__attribute__((address_space(3))) void*)l, 16, 0, 0);
}

// ---------------- weight f32 -> bf16 cast ----------------
__global__ __launch_bounds__(256) void wconv(const float* __restrict__ W,
                                             ushort* __restrict__ Wb, int n) {
  int i = (blockIdx.x * 256 + threadIdx.x) * 4;
  if (i < n) {
    float4 v = *(const float4*)(W + i);
    ushort4 o;
    o.x = f2bf(v.x); o.y = f2bf(v.y); o.z = f2bf(v.z); o.w = f2bf(v.w);
    *(ushort4*)(Wb + i) = o;
  }
}

// ---------------- EMA (exact equivalent of the FFT decay-mix) ----------------
// x_mix[t] = mix*x_mix[t-1] + (1-mix)*x[t],  x_mix[-1] = last_x
// Chunked over time with 128-step warmup (mix <= 0.731 -> mix^128 ~ 4e-18).
#define CHUNK 256
#define WARM 128
__global__ __launch_bounds__(256) void ema_kernel(
    const float* __restrict__ x,
    const float* __restrict__ mix_k, const float* __restrict__ mix_r,
    const float* __restrict__ lastk, const float* __restrict__ lastr,
    ushort* __restrict__ xmk, ushort* __restrict__ xmr) {
  const int d = blockIdx.y * 256 + threadIdx.x;
  const int c = blockIdx.x;
  const float mk = 1.f / (1.f + expf(-mix_k[d]));
  const float mr = 1.f / (1.f + expf(-mix_r[d]));
  const float omk = 1.f - mk, omr = 1.f - mr;
  float ak, ar;
  const int t0 = c * CHUNK;
  int tstart;
  if (c == 0) { ak = lastk[d]; ar = lastr[d]; tstart = 0; }
  else        { ak = 0.f;     ar = 0.f;      tstart = t0 - WARM; }
  for (int t = tstart; t < t0; ++t) {
    float xv = x[(size_t)t * DIM + d];
    ak = fmaf(mk, ak, omk * xv);
    ar = fmaf(mr, ar, omr * xv);
  }
  for (int t = t0; t < t0 + CHUNK; ++t) {
    float xv = x[(size_t)t * DIM + d];
    ak = fmaf(mk, ak, omk * xv);
    ar = fmaf(mr, ar, omr * xv);
    xmk[(size_t)t * DIM + d] = f2bf(ak);
    xmr[(size_t)t * DIM + d] = f2bf(ar);
  }
}

// ---------------- bf16 GEMM: C[m,n] = sum_k A[m,k] * B[n,k] ----------------
// 128x128 tile, BK=32, 4 waves (2x2), 4x4 16x16x32 frags per wave.
// EPI 0: Cb = bf16(relu(acc)^2)   (k path -> sq)
// EPI 1: Cf = sigmoid(acc)        (r path -> sig)
// EPI 2: Cf = Sig[o] * acc        (v path -> final out)
template <int EPI>
__global__ __launch_bounds__(256) void gemm_bt(
    const ushort* __restrict__ A, const ushort* __restrict__ B,
    float* __restrict__ Cf, ushort* __restrict__ Cb,
    const float* __restrict__ Sig, int M, int N, int K) {
  __shared__ __align__(16) ushort lA[128 * 32];
  __shared__ __align__(16) ushort lB[128 * 32];
  const int tid = threadIdx.x;
  const int lane = tid & 63;
  const int w = tid >> 6;
  const int wr = w >> 1, wc = w & 1;
  const int ntile = N / 128;
  const int tm = (blockIdx.x / ntile) * 128;
  const int tn = (blockIdx.x % ntile) * 128;

  f32x4 acc[4][4];
#pragma unroll
  for (int i = 0; i < 4; ++i)
#pragma unroll
    for (int j = 0; j < 4; ++j)
      acc[i][j] = (f32x4){0.f, 0.f, 0.f, 0.f};

  const int mrow = lane & 15;
  const int kof = (lane >> 4) * 8;

  for (int kt = 0; kt < K; kt += 32) {
#pragma unroll
    for (int it = 0; it < 2; ++it) {
      int li = it * 256 + tid;        // 0..511
      int r = li >> 2;                // row in tile
      int kc = (li & 3) << 3;         // k offset (x8 bf16)
      gll16(A + (size_t)(tm + r) * K + kt + kc, lA + li * 8);
      gll16(B + (size_t)(tn + r) * K + kt + kc, lB + li * 8);
    }
    __syncthreads();
    s16x8 af[4], bg[4];
#pragma unroll
    for (int i = 0; i < 4; ++i)
      af[i] = *(const s16x8*)(lA + (wr * 64 + i * 16 + mrow) * 32 + kof);
#pragma unroll
    for (int j = 0; j < 4; ++j)
      bg[j] = *(const s16x8*)(lB + (wc * 64 + j * 16 + mrow) * 32 + kof);
#pragma unroll
    for (int i = 0; i < 4; ++i)
#pragma unroll
      for (int j = 0; j < 4; ++j)
        acc[i][j] = __builtin_amdgcn_mfma_f32_16x16x32_bf16(af[i], bg[j], acc[i][j], 0, 0, 0);
    __syncthreads();
  }

#pragma unroll
  for (int i = 0; i < 4; ++i) {
#pragma unroll
    for (int j = 0; j < 4; ++j) {
      int col = tn + wc * 64 + j * 16 + (lane & 15);
#pragma unroll
      for (int q = 0; q < 4; ++q) {
        int row = tm + wr * 64 + i * 16 + (lane >> 4) * 4 + q;
        float v = acc[i][j][q];
        size_t o = (size_t)row * N + col;
        if (EPI == 0) {
          float rl = v > 0.f ? v : 0.f;
          Cb[o] = f2bf(rl * rl);
        } else if (EPI == 1) {
          Cf[o] = 1.f / (1.f + expf(-v));
        } else {
          Cf[o] = Sig[o] * v;
        }
      }
    }
  }
}

extern "C" void kernel_launch(void* const* d_in, const int* in_sizes, int n_in,
                              void* d_out, int out_size, void* d_ws, size_t ws_size,
                              hipStream_t stream) {
  const float* x    = (const float*)d_in[0];
  const float* Wk   = (const float*)d_in[1];
  const float* Wr   = (const float*)d_in[2];
  const float* Wv   = (const float*)d_in[3];
  const float* mixk = (const float*)d_in[4];
  const float* mixr = (const float*)d_in[5];
  const float* lxk  = (const float*)d_in[6];
  const float* lxr  = (const float*)d_in[7];
  float* out = (float*)d_out;

  char* ws = (char*)d_ws;
  ushort* xmk = (ushort*)(ws);                       // 16 MB  (4096x2048 bf16)
  ushort* xmr = (ushort*)(ws + (16u << 20));         // 16 MB
  ushort* Wkb = (ushort*)(ws + (32u << 20));         // 8 MB
  ushort* Wrb = (ushort*)(ws + (40u << 20));         // 8 MB
  ushort* Wvb = (ushort*)(ws + (48u << 20));         // 8 MB
  ushort* sq  = (ushort*)(ws + (56u << 20));         // 16 MB (bf16 relu(k)^2)
  float*  sig = (float*)(ws + (72u << 20));          // 32 MB (f32 sigmoid(r))
  // total 104 MB

  const int wn = DIM * DIM;
  wconv<<<wn / 1024, 256, 0, stream>>>(Wk, Wkb, wn);
  wconv<<<wn / 1024, 256, 0, stream>>>(Wr, Wrb, wn);
  wconv<<<wn / 1024, 256, 0, stream>>>(Wv, Wvb, wn);

  ema_kernel<<<dim3(LEN / CHUNK, DIM / 256), 256, 0, stream>>>(
      x, mixk, mixr, lxk, lxr, xmk, xmr);

  const int gT = (LEN / 128) * (DIM / 128);  // 512 blocks
  gemm_bt<0><<<gT, 256, 0, stream>>>(xmk, Wkb, nullptr, sq, nullptr, LEN, DIM, DIM);
  gemm_bt<1><<<gT, 256, 0, stream>>>(xmr, Wrb, sig, nullptr, nullptr, LEN, DIM, DIM);
  gemm_bt<2><<<gT, 256, 0, stream>>>(sq, Wvb, out, nullptr, sig, LEN, DIM, DIM);
}

// Round 2
// 333.579 us; speedup vs baseline: 1.1915x; 1.1915x over previous
//
#include <hip/hip_runtime.h>
#include <hip/hip_bf16.h>
#include <math.h>

#define LEN 4096
#define DIM 2048

typedef __attribute__((ext_vector_type(8))) short s16x8;
typedef __attribute__((ext_vector_type(4))) float f32x4;

__device__ inline ushort f2bf(float f) {
  union { float f; unsigned u; } v; v.f = f;
  unsigned r = (v.u + 0x7FFFu + ((v.u >> 16) & 1u)) >> 16;
  return (ushort)r;
}

__device__ inline void gll16(const void* g, void* l) {
  __builtin_amdgcn_global_load_lds(
      (const __attribute__((address_space(1))) void*)g,
      (__attribute__((address_space(3))) void*)l, 16, 0, 0);
}

// ---------------- weight f32 -> bf16 cast ----------------
__global__ __launch_bounds__(256) void wconv(const float* __restrict__ W,
                                             ushort* __restrict__ Wb, int n) {
  int i = (blockIdx.x * 256 + threadIdx.x) * 4;
  if (i < n) {
    float4 v = *(const float4*)(W + i);
    ushort4 o;
    o.x = f2bf(v.x); o.y = f2bf(v.y); o.z = f2bf(v.z); o.w = f2bf(v.w);
    *(ushort4*)(Wb + i) = o;
  }
}

// ---------------- EMA (exact equivalent of the FFT decay-mix) ----------------
// x_mix[t] = mix*x_mix[t-1] + (1-mix)*x[t],  x_mix[-1] = last_x
// CHUNK=64 with WARM=64: mix<=sigmoid(1)=0.731 -> 0.731^64 ~ 2e-9 (way below
// bf16 rounding). 512 blocks -> 2 blocks/CU instead of 128 blocks total.
#define CHUNK 64
#define WARM 64
__global__ __launch_bounds__(256) void ema_kernel(
    const float* __restrict__ x,
    const float* __restrict__ mix_k, const float* __restrict__ mix_r,
    const float* __restrict__ lastk, const float* __restrict__ lastr,
    ushort* __restrict__ xmk, ushort* __restrict__ xmr) {
  const int d = blockIdx.y * 256 + threadIdx.x;
  const int c = blockIdx.x;
  const float mk = 1.f / (1.f + expf(-mix_k[d]));
  const float mr = 1.f / (1.f + expf(-mix_r[d]));
  const float omk = 1.f - mk, omr = 1.f - mr;
  float ak, ar;
  const int t0 = c * CHUNK;
  if (c == 0) {
    ak = lastk[d]; ar = lastr[d];
  } else {
    ak = 0.f; ar = 0.f;
#pragma unroll 4
    for (int t = t0 - WARM; t < t0; ++t) {
      float xv = x[(size_t)t * DIM + d];
      ak = fmaf(mk, ak, omk * xv);
      ar = fmaf(mr, ar, omr * xv);
    }
  }
#pragma unroll 4
  for (int t = t0; t < t0 + CHUNK; ++t) {
    float xv = x[(size_t)t * DIM + d];
    ak = fmaf(mk, ak, omk * xv);
    ar = fmaf(mr, ar, omr * xv);
    xmk[(size_t)t * DIM + d] = f2bf(ak);
    xmr[(size_t)t * DIM + d] = f2bf(ar);
  }
}

// ---------------- bf16 GEMM: C[m,n] = sum_k A[m,k] * B[n,k] ----------------
// 128x128 tile, BK=32, 4 waves (2x2), 4x4 16x16x32 frags per wave.
// Body shared; epilogue per path.
template <int EPI>
__device__ __forceinline__ void gemm_body(
    const ushort* __restrict__ A, const ushort* __restrict__ B,
    float* __restrict__ Cf, ushort* __restrict__ Cb,
    const float* __restrict__ Sig, int bid, int M, int N, int K,
    ushort* lA, ushort* lB) {
  const int tid = threadIdx.x;
  const int lane = tid & 63;
  const int w = tid >> 6;
  const int wr = w >> 1, wc = w & 1;
  const int ntile = N / 128;
  const int tm = (bid / ntile) * 128;
  const int tn = (bid % ntile) * 128;

  f32x4 acc[4][4];
#pragma unroll
  for (int i = 0; i < 4; ++i)
#pragma unroll
    for (int j = 0; j < 4; ++j)
      acc[i][j] = (f32x4){0.f, 0.f, 0.f, 0.f};

  const int mrow = lane & 15;
  const int kof = (lane >> 4) * 8;

  for (int kt = 0; kt < K; kt += 32) {
#pragma unroll
    for (int it = 0; it < 2; ++it) {
      int li = it * 256 + tid;        // 0..511
      int r = li >> 2;                // row in tile
      int kc = (li & 3) << 3;         // k offset (x8 bf16)
      gll16(A + (size_t)(tm + r) * K + kt + kc, lA + li * 8);
      gll16(B + (size_t)(tn + r) * K + kt + kc, lB + li * 8);
    }
    __syncthreads();
    s16x8 af[4], bg[4];
#pragma unroll
    for (int i = 0; i < 4; ++i)
      af[i] = *(const s16x8*)(lA + (wr * 64 + i * 16 + mrow) * 32 + kof);
#pragma unroll
    for (int j = 0; j < 4; ++j)
      bg[j] = *(const s16x8*)(lB + (wc * 64 + j * 16 + mrow) * 32 + kof);
#pragma unroll
    for (int i = 0; i < 4; ++i)
#pragma unroll
      for (int j = 0; j < 4; ++j)
        acc[i][j] = __builtin_amdgcn_mfma_f32_16x16x32_bf16(af[i], bg[j], acc[i][j], 0, 0, 0);
    __syncthreads();
  }

#pragma unroll
  for (int i = 0; i < 4; ++i) {
#pragma unroll
    for (int j = 0; j < 4; ++j) {
      int col = tn + wc * 64 + j * 16 + (lane & 15);
#pragma unroll
      for (int q = 0; q < 4; ++q) {
        int row = tm + wr * 64 + i * 16 + (lane >> 4) * 4 + q;
        float v = acc[i][j][q];
        size_t o = (size_t)row * N + col;
        if (EPI == 0) {
          float rl = v > 0.f ? v : 0.f;
          Cb[o] = f2bf(rl * rl);
        } else if (EPI == 1) {
          Cf[o] = 1.f / (1.f + expf(-v));
        } else {
          Cf[o] = Sig[o] * v;
        }
      }
    }
  }
}

// Combined k+r GEMM: blocks [0,512) do k-path (relu^2 -> bf16 sq),
// blocks [512,1024) do r-path (sigmoid -> f32 sig). Single launch fills
// the machine better (1024 blocks) and overlaps the two tails.
__global__ __launch_bounds__(256) void gemm_kr(
    const ushort* __restrict__ Ak, const ushort* __restrict__ Bk,
    ushort* __restrict__ sq,
    const ushort* __restrict__ Ar, const ushort* __restrict__ Br,
    float* __restrict__ sig, int M, int N, int K, int nblk) {
  __shared__ __align__(16) ushort lA[128 * 32];
  __shared__ __align__(16) ushort lB[128 * 32];
  int bid = blockIdx.x;
  if (bid < nblk) {
    gemm_body<0>(Ak, Bk, nullptr, sq, nullptr, bid, M, N, K, lA, lB);
  } else {
    gemm_body<1>(Ar, Br, sig, nullptr, nullptr, bid - nblk, M, N, K, lA, lB);
  }
}

__global__ __launch_bounds__(256) void gemm_v(
    const ushort* __restrict__ A, const ushort* __restrict__ B,
    float* __restrict__ Cf, const float* __restrict__ Sig,
    int M, int N, int K) {
  __shared__ __align__(16) ushort lA[128 * 32];
  __shared__ __align__(16) ushort lB[128 * 32];
  gemm_body<2>(A, B, Cf, nullptr, Sig, blockIdx.x, M, N, K, lA, lB);
}

extern "C" void kernel_launch(void* const* d_in, const int* in_sizes, int n_in,
                              void* d_out, int out_size, void* d_ws, size_t ws_size,
                              hipStream_t stream) {
  const float* x    = (const float*)d_in[0];
  const float* Wk   = (const float*)d_in[1];
  const float* Wr   = (const float*)d_in[2];
  const float* Wv   = (const float*)d_in[3];
  const float* mixk = (const float*)d_in[4];
  const float* mixr = (const float*)d_in[5];
  const float* lxk  = (const float*)d_in[6];
  const float* lxr  = (const float*)d_in[7];
  float* out = (float*)d_out;

  char* ws = (char*)d_ws;
  ushort* xmk = (ushort*)(ws);                       // 16 MB  (4096x2048 bf16)
  ushort* xmr = (ushort*)(ws + (16u << 20));         // 16 MB
  ushort* Wkb = (ushort*)(ws + (32u << 20));         // 8 MB
  ushort* Wrb = (ushort*)(ws + (40u << 20));         // 8 MB
  ushort* Wvb = (ushort*)(ws + (48u << 20));         // 8 MB
  ushort* sq  = (ushort*)(ws + (56u << 20));         // 16 MB (bf16 relu(k)^2)
  float*  sig = (float*)(ws + (72u << 20));          // 32 MB (f32 sigmoid(r))
  // total 104 MB

  const int wn = DIM * DIM;
  wconv<<<wn / 1024, 256, 0, stream>>>(Wk, Wkb, wn);
  wconv<<<wn / 1024, 256, 0, stream>>>(Wr, Wrb, wn);
  wconv<<<wn / 1024, 256, 0, stream>>>(Wv, Wvb, wn);

  ema_kernel<<<dim3(LEN / CHUNK, DIM / 256), 256, 0, stream>>>(
      x, mixk, mixr, lxk, lxr, xmk, xmr);

  const int gT = (LEN / 128) * (DIM / 128);  // 512 blocks per GEMM
  gemm_kr<<<2 * gT, 256, 0, stream>>>(xmk, Wkb, sq, xmr, Wrb, sig,
                                      LEN, DIM, DIM, gT);
  gemm_v<<<gT, 256, 0, stream>>>(sq, Wvb, out, sig, LEN, DIM, DIM);
}

// Round 5
// 286.234 us; speedup vs baseline: 1.3886x; 1.1654x over previous
//
#include <hip/hip_runtime.h>
#include <hip/hip_bf16.h>
#include <math.h>

#define LEN 4096
#define DIM 2048

typedef __attribute__((ext_vector_type(8))) short s16x8;
typedef __attribute__((ext_vector_type(4))) float f32x4;

__device__ inline ushort f2bf(float f) {
  union { float f; unsigned u; } v; v.f = f;
  unsigned r = (v.u + 0x7FFFu + ((v.u >> 16) & 1u)) >> 16;
  return (ushort)r;
}

__device__ inline void gll16(const void* g, void* l) {
  __builtin_amdgcn_global_load_lds(
      (const __attribute__((address_space(1))) void*)g,
      (__attribute__((address_space(3))) void*)l, 16, 0, 0);
}

// ---------------- weight f32 -> bf16 cast (all 3 in one launch) ----------------
__global__ __launch_bounds__(256) void wconv3(
    const float* __restrict__ Wk, const float* __restrict__ Wr,
    const float* __restrict__ Wv, ushort* __restrict__ Wkb,
    ushort* __restrict__ Wrb, ushort* __restrict__ Wvb) {
  int b = blockIdx.x;                 // 0..12287
  int which = b >> 12;                // 4096 blocks per weight
  int i = (b & 4095) * 1024 + threadIdx.x * 4;
  const float* W = which == 0 ? Wk : which == 1 ? Wr : Wv;
  ushort* O = which == 0 ? Wkb : which == 1 ? Wrb : Wvb;
  float4 v = *(const float4*)(W + i);
  ushort4 o;
  o.x = f2bf(v.x); o.y = f2bf(v.y); o.z = f2bf(v.z); o.w = f2bf(v.w);
  *(ushort4*)(O + i) = o;
}

// ---------------- EMA (exact equivalent of the FFT decay-mix) ----------------
// x_mix[t] = mix*x_mix[t-1] + (1-mix)*x[t],  x_mix[-1] = last_x
// CHUNK=64 with WARM=64: mix<=sigmoid(1)=0.731 -> 0.731^64 ~ 2e-9.
#define CHUNK 64
#define WARM 64
__global__ __launch_bounds__(256) void ema_kernel(
    const float* __restrict__ x,
    const float* __restrict__ mix_k, const float* __restrict__ mix_r,
    const float* __restrict__ lastk, const float* __restrict__ lastr,
    ushort* __restrict__ xmk, ushort* __restrict__ xmr) {
  const int d = blockIdx.y * 256 + threadIdx.x;
  const int c = blockIdx.x;
  const float mk = 1.f / (1.f + expf(-mix_k[d]));
  const float mr = 1.f / (1.f + expf(-mix_r[d]));
  const float omk = 1.f - mk, omr = 1.f - mr;
  float ak, ar;
  const int t0 = c * CHUNK;
  if (c == 0) {
    ak = lastk[d]; ar = lastr[d];
  } else {
    ak = 0.f; ar = 0.f;
#pragma unroll 4
    for (int t = t0 - WARM; t < t0; ++t) {
      float xv = x[(size_t)t * DIM + d];
      ak = fmaf(mk, ak, omk * xv);
      ar = fmaf(mr, ar, omr * xv);
    }
  }
#pragma unroll 4
  for (int t = t0; t < t0 + CHUNK; ++t) {
    float xv = x[(size_t)t * DIM + d];
    ak = fmaf(mk, ak, omk * xv);
    ar = fmaf(mr, ar, omr * xv);
    xmk[(size_t)t * DIM + d] = f2bf(ak);
    xmr[(size_t)t * DIM + d] = f2bf(ar);
  }
}

// ---------------- 8-phase 256x256 BK=64 bf16 GEMM (m201-style template) ------
// C[m,n] = sum_k A[m,k]*B[n,k].  8 waves (2M x 4N), per-wave 128x64 out.
// LDS 128KB: 2 dbuf x (A 256x64 + B 256x64) bf16, each tile as 2 halves of
// 128x64. XOR swizzle seg^=(row&7) applied on BOTH sides (inverse-swizzled
// global source for global_load_lds + swizzled ds_read).
// vmcnt ledger (per-wave in-order queue, 2 loads per stage call):
//   ph4 VM4 retires {prev ph7,ph8; ph1,ph2} -> buf1.B(prev k3) + buf1.A(k1)
//   ph8 VM4 retires {ph3..ph6}              -> all of buf0(k2)
// so every read phase touches only landed regions; stage-overwrites are
// issued only after the closing barrier of the last consuming phase.
#define BAR() __builtin_amdgcn_s_barrier()
#define LGKM0() asm volatile("s_waitcnt lgkmcnt(0)")
#define VM4() asm volatile("s_waitcnt vmcnt(4)" ::: "memory")

template <int EPI>
__device__ __forceinline__ void gemm8_body(
    const ushort* __restrict__ A, const ushort* __restrict__ B,
    float* __restrict__ Cf, ushort* __restrict__ Cb,
    const float* __restrict__ Sig, int bid, ushort* lds0, ushort* lds1) {
  const int N = DIM, K = DIM;
  const int tid = threadIdx.x;
  const int lane = tid & 63;
  const int w = tid >> 6;     // 0..7
  const int wr = w >> 2;      // 0..1
  const int wc = w & 3;       // 0..3
  const int tm = (bid >> 3) * 256;  // 16 M-tiles
  const int tn = (bid & 7) * 256;   // 8 N-tiles

  f32x4 acc[8][4];
#pragma unroll
  for (int i = 0; i < 8; ++i)
#pragma unroll
    for (int j = 0; j < 4; ++j)
      acc[i][j] = (f32x4){0.f, 0.f, 0.f, 0.f};

  const int sr = tid >> 3;          // staging row 0..63
  const int ssw = ((tid & 7) ^ (sr & 7)) << 3;  // inverse-swizzled k-seg (elems)

  auto stA = [&](ushort* buf, int h, int kt) {
    ushort* dst = buf + h * 8192;
    int ke = kt * 64 + ssw;
    gll16(A + (size_t)(tm + h * 128 + sr) * K + ke, dst + tid * 8);
    gll16(A + (size_t)(tm + h * 128 + 64 + sr) * K + ke, dst + 4096 + tid * 8);
  };
  auto stB = [&](ushort* buf, int h, int kt) {
    ushort* dst = buf + 16384 + h * 8192;
    int ke = kt * 64 + ssw;
    gll16(B + (size_t)(tn + h * 128 + sr) * K + ke, dst + tid * 8);
    gll16(B + (size_t)(tn + h * 128 + 64 + sr) * K + ke, dst + 4096 + tid * 8);
  };

  s16x8 af[4][2], bf[4][2];
  auto rdA = [&](const ushort* buf, int qm) {
#pragma unroll
    for (int i = 0; i < 4; ++i)
#pragma unroll
      for (int kk = 0; kk < 2; ++kk) {
        int rr = (qm * 4 + i) * 16 + (lane & 15);   // rr&7 == lane&7
        int segp = ((kk << 2) + (lane >> 4)) ^ (lane & 7);
        af[i][kk] = *(const s16x8*)(buf + wr * 8192 + rr * 64 + segp * 8);
      }
  };
  auto rdB2 = [&](const ushort* buf, int qn) {
#pragma unroll
    for (int j = 0; j < 2; ++j)
#pragma unroll
      for (int kk = 0; kk < 2; ++kk) {
        int nn = wc * 64 + (qn * 2 + j) * 16 + (lane & 15);  // nn&7 == lane&7
        int segp = ((kk << 2) + (lane >> 4)) ^ (lane & 7);
        bf[qn * 2 + j][kk] =
            *(const s16x8*)(buf + 16384 + (nn >> 7) * 8192 + (nn & 127) * 64 + segp * 8);
      }
  };
  auto mm = [&](int qm, int qn) {
    __builtin_amdgcn_s_setprio(1);
#pragma unroll
    for (int i = 0; i < 4; ++i)
#pragma unroll
      for (int j = 0; j < 2; ++j)
#pragma unroll
        for (int kk = 0; kk < 2; ++kk)
          acc[qm * 4 + i][qn * 2 + j] = __builtin_amdgcn_mfma_f32_16x16x32_bf16(
              af[i][kk], bf[qn * 2 + j][kk], acc[qm * 4 + i][qn * 2 + j], 0, 0, 0);
    __builtin_amdgcn_s_setprio(0);
  };

  // prologue: buf0 <- K0 (all 4 halves), buf1.B <- K1
  stA(lds0, 0, 0); stA(lds0, 1, 0); stB(lds0, 0, 0); stB(lds0, 1, 0);
  stB(lds1, 0, 1); stB(lds1, 1, 1);
  VM4();  // oldest 8 (all of buf0) landed
  BAR();

  for (int u = 0; u < 16; ++u) {
    int k1 = 2 * u + 1;
    int k2 = 2 * u + 2 < 32 ? 2 * u + 2 : 31;  // tail: restage tile 31 (unread)
    int k3 = 2 * u + 3 < 32 ? 2 * u + 3 : 31;
    // ph1
    rdA(lds0, 0); rdB2(lds0, 0); stA(lds1, 0, k1);
    BAR(); LGKM0(); mm(0, 0); BAR();
    // ph2
    rdB2(lds0, 1); stA(lds1, 1, k1);
    BAR(); LGKM0(); mm(0, 1); BAR();
    // ph3
    rdA(lds0, 1); stB(lds0, 0, k2);
    BAR(); LGKM0(); mm(1, 0); BAR();
    // ph4
    stB(lds0, 1, k2); VM4();
    BAR(); mm(1, 1); BAR();
    // ph5
    rdA(lds1, 0); rdB2(lds1, 0); stA(lds0, 0, k2);
    BAR(); LGKM0(); mm(0, 0); BAR();
    // ph6
    rdB2(lds1, 1); stA(lds0, 1, k2);
    BAR(); LGKM0(); mm(0, 1); BAR();
    // ph7
    rdA(lds1, 1); stB(lds1, 0, k3);
    BAR(); LGKM0(); mm(1, 0); BAR();
    // ph8
    stB(lds1, 1, k3); VM4();
    BAR(); mm(1, 1); BAR();
  }

#pragma unroll
  for (int i = 0; i < 8; ++i)
#pragma unroll
    for (int j = 0; j < 4; ++j) {
      int col = tn + wc * 64 + j * 16 + (lane & 15);
#pragma unroll
      for (int q = 0; q < 4; ++q) {
        int row = tm + wr * 128 + i * 16 + (lane >> 4) * 4 + q;
        float v = acc[i][j][q];
        size_t o = (size_t)row * N + col;
        if (EPI == 0) {
          float rl = v > 0.f ? v : 0.f;
          Cb[o] = f2bf(rl * rl);
        } else if (EPI == 1) {
          Cf[o] = 1.f / (1.f + expf(-v));
        } else {
          Cf[o] = Sig[o] * v;
        }
      }
    }
}

// k+r fused: blocks [0,128) k-path, [128,256) r-path
__global__ __launch_bounds__(512, 2) void gemm_kr(
    const ushort* __restrict__ Ak, const ushort* __restrict__ Bk,
    ushort* __restrict__ sq,
    const ushort* __restrict__ Ar, const ushort* __restrict__ Br,
    float* __restrict__ sig) {
  __shared__ __align__(16) ushort lds[2][32768];
  int bid = blockIdx.x;
  if (bid < 128)
    gemm8_body<0>(Ak, Bk, nullptr, sq, nullptr, bid, lds[0], lds[1]);
  else
    gemm8_body<1>(Ar, Br, sig, nullptr, nullptr, bid - 128, lds[0], lds[1]);
}

__global__ __launch_bounds__(512, 2) void gemm_v(
    const ushort* __restrict__ A, const ushort* __restrict__ B,
    float* __restrict__ Cf, const float* __restrict__ Sig) {
  __shared__ __align__(16) ushort lds[2][32768];
  gemm8_body<2>(A, B, Cf, nullptr, Sig, blockIdx.x, lds[0], lds[1]);
}

extern "C" void kernel_launch(void* const* d_in, const int* in_sizes, int n_in,
                              void* d_out, int out_size, void* d_ws, size_t ws_size,
                              hipStream_t stream) {
  const float* x    = (const float*)d_in[0];
  const float* Wk   = (const float*)d_in[1];
  const float* Wr   = (const float*)d_in[2];
  const float* Wv   = (const float*)d_in[3];
  const float* mixk = (const float*)d_in[4];
  const float* mixr = (const float*)d_in[5];
  const float* lxk  = (const float*)d_in[6];
  const float* lxr  = (const float*)d_in[7];
  float* out = (float*)d_out;

  char* ws = (char*)d_ws;
  ushort* xmk = (ushort*)(ws);                       // 16 MB
  ushort* xmr = (ushort*)(ws + (16u << 20));         // 16 MB
  ushort* Wkb = (ushort*)(ws + (32u << 20));         // 8 MB
  ushort* Wrb = (ushort*)(ws + (40u << 20));         // 8 MB
  ushort* Wvb = (ushort*)(ws + (48u << 20));         // 8 MB
  ushort* sq  = (ushort*)(ws + (56u << 20));         // 16 MB
  float*  sig = (float*)(ws + (72u << 20));          // 32 MB

  wconv3<<<3 * 4096, 256, 0, stream>>>(Wk, Wr, Wv, Wkb, Wrb, Wvb);

  ema_kernel<<<dim3(LEN / CHUNK, DIM / 256), 256, 0, stream>>>(
      x, mixk, mixr, lxk, lxr, xmk, xmr);

  gemm_kr<<<256, 512, 0, stream>>>(xmk, Wkb, sq, xmr, Wrb, sig);
  gemm_v<<<128, 512, 0, stream>>>(sq, Wvb, out, sig);
}

// Round 6
// 276.345 us; speedup vs baseline: 1.4383x; 1.0358x over previous
//
#include <hip/hip_runtime.h>
#include <hip/hip_bf16.h>
#include <math.h>

#define LEN 4096
#define DIM 2048

typedef __attribute__((ext_vector_type(8))) short s16x8;
typedef __attribute__((ext_vector_type(4))) float f32x4;

__device__ inline ushort f2bf(float f) {
  union { float f; unsigned u; } v; v.f = f;
  unsigned r = (v.u + 0x7FFFu + ((v.u >> 16) & 1u)) >> 16;
  return (ushort)r;
}

__device__ inline float bf2f(ushort b) {
  union { unsigned u; float f; } v; v.u = ((unsigned)b) << 16;
  return v.f;
}

__device__ inline void gll16(const void* g, void* l) {
  __builtin_amdgcn_global_load_lds(
      (const __attribute__((address_space(1))) void*)g,
      (__attribute__((address_space(3))) void*)l, 16, 0, 0);
}

// ---------------- weight f32 -> bf16 cast (all 3 in one launch) ----------------
__global__ __launch_bounds__(256) void wconv3(
    const float* __restrict__ Wk, const float* __restrict__ Wr,
    const float* __restrict__ Wv, ushort* __restrict__ Wkb,
    ushort* __restrict__ Wrb, ushort* __restrict__ Wvb) {
  int b = blockIdx.x;                 // 0..12287
  int which = b >> 12;                // 4096 blocks per weight
  int i = (b & 4095) * 1024 + threadIdx.x * 4;
  const float* W = which == 0 ? Wk : which == 1 ? Wr : Wv;
  ushort* O = which == 0 ? Wkb : which == 1 ? Wrb : Wvb;
  float4 v = *(const float4*)(W + i);
  ushort4 o;
  o.x = f2bf(v.x); o.y = f2bf(v.y); o.z = f2bf(v.z); o.w = f2bf(v.w);
  *(ushort4*)(O + i) = o;
}

// ---------------- EMA (exact equivalent of the FFT decay-mix) ----------------
// x_mix[t] = mix*x_mix[t-1] + (1-mix)*x[t],  x_mix[-1] = last_x
// CHUNK=64 with WARM=64: mix<=sigmoid(1)=0.731 -> 0.731^64 ~ 2e-9.
#define CHUNK 64
#define WARM 64
__global__ __launch_bounds__(256) void ema_kernel(
    const float* __restrict__ x,
    const float* __restrict__ mix_k, const float* __restrict__ mix_r,
    const float* __restrict__ lastk, const float* __restrict__ lastr,
    ushort* __restrict__ xmk, ushort* __restrict__ xmr) {
  const int d = blockIdx.y * 256 + threadIdx.x;
  const int c = blockIdx.x;
  const float mk = 1.f / (1.f + expf(-mix_k[d]));
  const float mr = 1.f / (1.f + expf(-mix_r[d]));
  const float omk = 1.f - mk, omr = 1.f - mr;
  float ak, ar;
  const int t0 = c * CHUNK;
  if (c == 0) {
    ak = lastk[d]; ar = lastr[d];
  } else {
    ak = 0.f; ar = 0.f;
#pragma unroll 4
    for (int t = t0 - WARM; t < t0; ++t) {
      float xv = x[(size_t)t * DIM + d];
      ak = fmaf(mk, ak, omk * xv);
      ar = fmaf(mr, ar, omr * xv);
    }
  }
#pragma unroll 4
  for (int t = t0; t < t0 + CHUNK; ++t) {
    float xv = x[(size_t)t * DIM + d];
    ak = fmaf(mk, ak, omk * xv);
    ar = fmaf(mr, ar, omr * xv);
    xmk[(size_t)t * DIM + d] = f2bf(ak);
    xmr[(size_t)t * DIM + d] = f2bf(ar);
  }
}

// ---------------- 8-phase 256x256 BK=64 bf16 GEMM (m201-style template) ------
// C[m,n] = sum_k A[m,k]*B[n,k].  8 waves (2M x 4N), per-wave 128x64 out.
// LDS 128KB: 2 dbuf x (A 256x64 + B 256x64) bf16, each tile as 2 halves of
// 128x64. XOR swizzle seg^=(row&7) applied on BOTH sides (inverse-swizzled
// global source for global_load_lds + swizzled ds_read).
// vmcnt ledger (per-wave in-order queue, 2 loads per stage call):
//   ph4 VM4 retires {prev ph7,ph8; ph1,ph2} -> buf1.B(prev k3) + buf1.A(k1)
//   ph8 VM4 retires {ph3..ph6}              -> all of buf0(k2)
// so every read phase touches only landed regions; stage-overwrites are
// issued only after the closing barrier of the last consuming phase.
// EPI 0: sq  = bf16(relu(acc)^2)
// EPI 1: sig = bf16(sigmoid(acc))       (bf16 to halve epilogue traffic)
// EPI 2: out = bf16->f32(Sig[o]) * acc  (f32 final output)
#define BAR() __builtin_amdgcn_s_barrier()
#define LGKM0() asm volatile("s_waitcnt lgkmcnt(0)")
#define VM4() asm volatile("s_waitcnt vmcnt(4)" ::: "memory")

template <int EPI>
__device__ __forceinline__ void gemm8_body(
    const ushort* __restrict__ A, const ushort* __restrict__ B,
    float* __restrict__ Cf, ushort* __restrict__ Cb,
    const ushort* __restrict__ Sig, int bid, ushort* lds0, ushort* lds1) {
  const int N = DIM, K = DIM;
  const int tid = threadIdx.x;
  const int lane = tid & 63;
  const int w = tid >> 6;     // 0..7
  const int wr = w >> 2;      // 0..1
  const int wc = w & 3;       // 0..3
  const int tm = (bid >> 3) * 256;  // 16 M-tiles
  const int tn = (bid & 7) * 256;   // 8 N-tiles

  f32x4 acc[8][4];
#pragma unroll
  for (int i = 0; i < 8; ++i)
#pragma unroll
    for (int j = 0; j < 4; ++j)
      acc[i][j] = (f32x4){0.f, 0.f, 0.f, 0.f};

  const int sr = tid >> 3;          // staging row 0..63
  const int ssw = ((tid & 7) ^ (sr & 7)) << 3;  // inverse-swizzled k-seg (elems)

  auto stA = [&](ushort* buf, int h, int kt) {
    ushort* dst = buf + h * 8192;
    int ke = kt * 64 + ssw;
    gll16(A + (size_t)(tm + h * 128 + sr) * K + ke, dst + tid * 8);
    gll16(A + (size_t)(tm + h * 128 + 64 + sr) * K + ke, dst + 4096 + tid * 8);
  };
  auto stB = [&](ushort* buf, int h, int kt) {
    ushort* dst = buf + 16384 + h * 8192;
    int ke = kt * 64 + ssw;
    gll16(B + (size_t)(tn + h * 128 + sr) * K + ke, dst + tid * 8);
    gll16(B + (size_t)(tn + h * 128 + 64 + sr) * K + ke, dst + 4096 + tid * 8);
  };

  s16x8 af[4][2], bf[4][2];
  auto rdA = [&](const ushort* buf, int qm) {
#pragma unroll
    for (int i = 0; i < 4; ++i)
#pragma unroll
      for (int kk = 0; kk < 2; ++kk) {
        int rr = (qm * 4 + i) * 16 + (lane & 15);   // rr&7 == lane&7
        int segp = ((kk << 2) + (lane >> 4)) ^ (lane & 7);
        af[i][kk] = *(const s16x8*)(buf + wr * 8192 + rr * 64 + segp * 8);
      }
  };
  auto rdB2 = [&](const ushort* buf, int qn) {
#pragma unroll
    for (int j = 0; j < 2; ++j)
#pragma unroll
      for (int kk = 0; kk < 2; ++kk) {
        int nn = wc * 64 + (qn * 2 + j) * 16 + (lane & 15);  // nn&7 == lane&7
        int segp = ((kk << 2) + (lane >> 4)) ^ (lane & 7);
        bf[qn * 2 + j][kk] =
            *(const s16x8*)(buf + 16384 + (nn >> 7) * 8192 + (nn & 127) * 64 + segp * 8);
      }
  };
  auto mm = [&](int qm, int qn) {
    __builtin_amdgcn_s_setprio(1);
#pragma unroll
    for (int i = 0; i < 4; ++i)
#pragma unroll
      for (int j = 0; j < 2; ++j)
#pragma unroll
        for (int kk = 0; kk < 2; ++kk)
          acc[qm * 4 + i][qn * 2 + j] = __builtin_amdgcn_mfma_f32_16x16x32_bf16(
              af[i][kk], bf[qn * 2 + j][kk], acc[qm * 4 + i][qn * 2 + j], 0, 0, 0);
    __builtin_amdgcn_s_setprio(0);
  };

  // prologue: buf0 <- K0 (all 4 halves), buf1.B <- K1
  stA(lds0, 0, 0); stA(lds0, 1, 0); stB(lds0, 0, 0); stB(lds0, 1, 0);
  stB(lds1, 0, 1); stB(lds1, 1, 1);
  VM4();  // oldest 8 (all of buf0) landed
  BAR();

  for (int u = 0; u < 16; ++u) {
    int k1 = 2 * u + 1;
    int k2 = 2 * u + 2 < 32 ? 2 * u + 2 : 31;  // tail: restage tile 31 (unread)
    int k3 = 2 * u + 3 < 32 ? 2 * u + 3 : 31;
    // ph1
    rdA(lds0, 0); rdB2(lds0, 0); stA(lds1, 0, k1);
    BAR(); LGKM0(); mm(0, 0); BAR();
    // ph2
    rdB2(lds0, 1); stA(lds1, 1, k1);
    BAR(); LGKM0(); mm(0, 1); BAR();
    // ph3
    rdA(lds0, 1); stB(lds0, 0, k2);
    BAR(); LGKM0(); mm(1, 0); BAR();
    // ph4
    stB(lds0, 1, k2); VM4();
    BAR(); mm(1, 1); BAR();
    // ph5
    rdA(lds1, 0); rdB2(lds1, 0); stA(lds0, 0, k2);
    BAR(); LGKM0(); mm(0, 0); BAR();
    // ph6
    rdB2(lds1, 1); stA(lds0, 1, k2);
    BAR(); LGKM0(); mm(0, 1); BAR();
    // ph7
    rdA(lds1, 1); stB(lds1, 0, k3);
    BAR(); LGKM0(); mm(1, 0); BAR();
    // ph8
    stB(lds1, 1, k3); VM4();
    BAR(); mm(1, 1); BAR();
  }

#pragma unroll
  for (int i = 0; i < 8; ++i)
#pragma unroll
    for (int j = 0; j < 4; ++j) {
      int col = tn + wc * 64 + j * 16 + (lane & 15);
#pragma unroll
      for (int q = 0; q < 4; ++q) {
        int row = tm + wr * 128 + i * 16 + (lane >> 4) * 4 + q;
        float v = acc[i][j][q];
        size_t o = (size_t)row * N + col;
        if (EPI == 0) {
          float rl = v > 0.f ? v : 0.f;
          Cb[o] = f2bf(rl * rl);
        } else if (EPI == 1) {
          Cb[o] = f2bf(1.f / (1.f + expf(-v)));
        } else {
          Cf[o] = bf2f(Sig[o]) * v;
        }
      }
    }
}

// k+r fused, XCD-contiguous swizzle: lbid = (bid&7)*32 + bid>>3.
// XCD j (= bid&7, round-robin dispatch) owns logical blocks [32j, 32j+32):
// one path, 4 contiguous tm panels (4MB A, L2-resident), all 8 tn.
// Same-tm blocks now share one XCD's L2 -> A fetched once, not 8x from L3.
__global__ __launch_bounds__(512, 2) void gemm_kr(
    const ushort* __restrict__ Ak, const ushort* __restrict__ Bk,
    ushort* __restrict__ sq,
    const ushort* __restrict__ Ar, const ushort* __restrict__ Br,
    ushort* __restrict__ sig) {
  __shared__ __align__(16) ushort lds[2][32768];
  int lbid = (blockIdx.x & 7) * 32 + (blockIdx.x >> 3);
  if (lbid < 128)
    gemm8_body<0>(Ak, Bk, nullptr, sq, nullptr, lbid, lds[0], lds[1]);
  else
    gemm8_body<1>(Ar, Br, nullptr, sig, nullptr, lbid - 128, lds[0], lds[1]);
}

__global__ __launch_bounds__(512, 2) void gemm_v(
    const ushort* __restrict__ A, const ushort* __restrict__ B,
    float* __restrict__ Cf, const ushort* __restrict__ Sig) {
  __shared__ __align__(16) ushort lds[2][32768];
  int lbid = (blockIdx.x & 7) * 16 + (blockIdx.x >> 3);
  gemm8_body<2>(A, B, Cf, nullptr, Sig, lbid, lds[0], lds[1]);
}

extern "C" void kernel_launch(void* const* d_in, const int* in_sizes, int n_in,
                              void* d_out, int out_size, void* d_ws, size_t ws_size,
                              hipStream_t stream) {
  const float* x    = (const float*)d_in[0];
  const float* Wk   = (const float*)d_in[1];
  const float* Wr   = (const float*)d_in[2];
  const float* Wv   = (const float*)d_in[3];
  const float* mixk = (const float*)d_in[4];
  const float* mixr = (const float*)d_in[5];
  const float* lxk  = (const float*)d_in[6];
  const float* lxr  = (const float*)d_in[7];
  float* out = (float*)d_out;

  char* ws = (char*)d_ws;
  ushort* xmk = (ushort*)(ws);                       // 16 MB
  ushort* xmr = (ushort*)(ws + (16u << 20));         // 16 MB
  ushort* Wkb = (ushort*)(ws + (32u << 20));         // 8 MB
  ushort* Wrb = (ushort*)(ws + (40u << 20));         // 8 MB
  ushort* Wvb = (ushort*)(ws + (48u << 20));         // 8 MB
  ushort* sq  = (ushort*)(ws + (56u << 20));         // 16 MB
  ushort* sig = (ushort*)(ws + (72u << 20));         // 16 MB (bf16 sigmoid(r))

  wconv3<<<3 * 4096, 256, 0, stream>>>(Wk, Wr, Wv, Wkb, Wrb, Wvb);

  ema_kernel<<<dim3(LEN / CHUNK, DIM / 256), 256, 0, stream>>>(
      x, mixk, mixr, lxk, lxr, xmk, xmr);

  gemm_kr<<<256, 512, 0, stream>>>(xmk, Wkb, sq, xmr, Wrb, sig);
  gemm_v<<<128, 512, 0, stream>>>(sq, Wvb, out, sig);
}